// Round 13
// baseline (283.331 us; speedup 1.0000x reference)
//
#include <hip/hip_runtime.h>

#define D 64
#define NREL 3
#define SRC_MASK 0x07FFFFFF
#define ATHR 512
#define APT 8
#define ABLK (ATHR * APT)        // 4096 edges per block (bhist)
#define APT2 32
#define ABLK2 (ATHR * APT2)      // 16384 edges per block (binA: long runs -> low write amp)

typedef unsigned short bf16_t;
typedef __attribute__((ext_vector_type(8))) short short8v;   // 8 bf16 = 4 VGPRs
typedef __attribute__((ext_vector_type(4))) float float4v;

__device__ __forceinline__ float bf2f(unsigned int u16) {
  return __uint_as_float(u16 << 16);
}
__device__ __forceinline__ unsigned int f2bf(float f) {
  unsigned int x = __float_as_uint(f);
  return (x + 0x7fffu + ((x >> 16) & 1u)) >> 16;  // round-to-nearest-even
}

// ---------------- tiny zero (replaces 2x hipMemsetAsync: each cost ~40us of
// fill-kernel overhead for 1.5 KB in R12's profile) ----------------
__global__ __launch_bounds__(512) void zero_kernel(int* __restrict__ a,
                                                   int* __restrict__ b, int n) {
  const int t = threadIdx.x;
  for (int i = t; i < n; i += 512) { a[i] = 0; b[i] = 0; }
}

// ---------------- f32 -> bf16 convert (for layer-1 input) ----------------
__global__ __launch_bounds__(256) void conv_kernel(
    const float* __restrict__ in, bf16_t* __restrict__ out, int n4) {
  const int i = blockIdx.x * 256 + threadIdx.x;
  if (i >= n4) return;
  const float4 f = reinterpret_cast<const float4*>(in)[i];
  uint2 o;
  o.x = f2bf(f.x) | (f2bf(f.y) << 16);
  o.y = f2bf(f.z) | (f2bf(f.w) << 16);
  reinterpret_cast<uint2*>(out)[i] = o;
}

// ---------------- transform via MFMA (R11-verified: 4x faster than VALU) ----------
__global__ __launch_bounds__(256) void transform_kernel(
    const bf16_t* __restrict__ xb, const float* __restrict__ W,
    bf16_t* __restrict__ hr, int n_nodes) {
  __shared__ bf16_t wt[NREL * 64 * 72];  // 27.6 KB
  const int tid = threadIdx.x;

  for (int idx = tid; idx < NREL * 64 * 64; idx += 256) {
    const int r = idx >> 12;
    const int k = (idx >> 6) & 63;
    const int od = idx & 63;
    wt[(r * 64 + od) * 72 + k] = (bf16_t)f2bf(W[idx]);
  }
  __syncthreads();

  const int wid = tid >> 6;
  const int lane = tid & 63;
  const int n0 = blockIdx.x * 64 + wid * 16;
  if (n0 >= n_nodes) return;

  const bf16_t* xrow = &xb[(long)(n0 + (lane & 15)) * 64 + (lane >> 4) * 8];
  const short8v bx0 = *reinterpret_cast<const short8v*>(xrow);
  const short8v bx1 = *reinterpret_cast<const short8v*>(xrow + 32);

  const int node = n0 + (lane & 15);
#pragma unroll
  for (int r = 0; r < NREL; ++r) {
#pragma unroll
    for (int t = 0; t < 4; ++t) {
      const bf16_t* wrow =
          &wt[(r * 64 + t * 16 + (lane & 15)) * 72 + (lane >> 4) * 8];
      const short8v a0 = *reinterpret_cast<const short8v*>(wrow);
      const short8v a1 = *reinterpret_cast<const short8v*>(wrow + 32);
      float4v acc = {0.f, 0.f, 0.f, 0.f};
      acc = __builtin_amdgcn_mfma_f32_16x16x32_bf16(a0, bx0, acc, 0, 0, 0);
      acc = __builtin_amdgcn_mfma_f32_16x16x32_bf16(a1, bx1, acc, 0, 0, 0);
      const int od = t * 16 + (lane >> 4) * 4;
      uint2 o;
      o.x = f2bf(acc[0]) | (f2bf(acc[1]) << 16);
      o.y = f2bf(acc[2]) | (f2bf(acc[3]) << 16);
      *reinterpret_cast<uint2*>(&hr[((long)r * n_nodes + node) * 64 + od]) = o;
    }
  }
}

// ---------------- CSR build (bucket-level only; no node-level atomics) ----------
__global__ __launch_bounds__(ATHR) void bhist_kernel(
    const int* __restrict__ dst, int* __restrict__ bdeg, int n_edges, int nb) {
  __shared__ int cnt[400];
  const int t = threadIdx.x;
  for (int b = t; b < nb; b += ATHR) cnt[b] = 0;
  __syncthreads();
  const long e0 = (long)blockIdx.x * ABLK;
#pragma unroll
  for (int i = 0; i < APT; ++i) {
    const long e = e0 + t + (long)i * ATHR;
    if (e < n_edges) atomicAdd(&cnt[dst[e] >> 8], 1);
  }
  __syncthreads();
  for (int b = t; b < nb; b += ATHR)
    if (cnt[b]) atomicAdd(&bdeg[b], cnt[b]);
}

// Single block: exclusive scan of bdeg[nb] -> boffs[nb+1] (nb <= 512).
__global__ __launch_bounds__(512) void bscan_kernel(
    const int* __restrict__ bdeg, int* __restrict__ boffs, int nb) {
  __shared__ int s[512];
  const int t = threadIdx.x;
  const int v = (t < nb) ? bdeg[t] : 0;
  s[t] = v;
  __syncthreads();
  for (int off = 1; off < 512; off <<= 1) {
    const int add = (t >= off) ? s[t - off] : 0;
    __syncthreads();
    s[t] += add;
    __syncthreads();
  }
  if (t < nb) boffs[t] = s[t] - v;
  if (t == 511) boffs[nb] = s[nb - 1];
}

// Phase A (two-pass, 16K edges/block): pass1 counts per bucket in LDS (no
// payload regs), one reserve atomic per (block,bucket) -> per-bucket runs of
// ~42 edges (336 B) -> write amp ~1.3x (was ~10-edge runs, 2.75x, 42 us).
__global__ __launch_bounds__(ATHR) void binA_kernel(
    const int* __restrict__ src, const int* __restrict__ dst,
    const int* __restrict__ rel, const float* __restrict__ norm,
    const int* __restrict__ boffs, int* __restrict__ bcur,
    int2* __restrict__ binpay, unsigned char* __restrict__ bindst,
    int n_edges, int nb) {
  __shared__ int cnt[400];
  __shared__ int cur[400];
  const int t = threadIdx.x;
  const long e0 = (long)blockIdx.x * ABLK2;

  for (int b = t; b < nb; b += ATHR) cnt[b] = 0;
  __syncthreads();

  // pass 1: count
#pragma unroll 4
  for (int i = 0; i < APT2; ++i) {
    const long e = e0 + t + (long)i * ATHR;
    if (e < n_edges) atomicAdd(&cnt[dst[e] >> 8], 1);
  }
  __syncthreads();

  // reserve contiguous range per bucket
  for (int b = t; b < nb; b += ATHR) {
    const int c = cnt[b];
    cur[b] = c ? (boffs[b] + atomicAdd(&bcur[b], c)) : 0;
  }
  __syncthreads();

  // pass 2: place
#pragma unroll 4
  for (int i = 0; i < APT2; ++i) {
    const long e = e0 + t + (long)i * ATHR;
    if (e < n_edges) {
      const int d = dst[e];
      const int pos = atomicAdd(&cur[d >> 8], 1);
      binpay[pos] = make_int2(src[e] | (rel[e] << 27), __float_as_int(norm[e]));
      bindst[pos] = (unsigned char)(d & 255);
    }
  }
}

// Phase B: one block per bucket. Pass 1: count per-node edges in LDS, LDS
// exclusive scan -> write deg/offs to global. Pass 2: place edges at exact
// CSR position via LDS cursors. No global atomics.
__global__ __launch_bounds__(256) void binB_kernel(
    const int2* __restrict__ binpay, const unsigned char* __restrict__ bindst,
    const int* __restrict__ boffs, int2* __restrict__ edgebuf,
    int* __restrict__ deg, int* __restrict__ offs, int n_nodes) {
  __shared__ int cnt[256];
  __shared__ int ss[256];
  __shared__ int cur[256];
  const int b = blockIdx.x;
  const int t = threadIdx.x;
  cnt[t] = 0;
  __syncthreads();
  const int start = boffs[b];
  const int end = boffs[b + 1];
  for (int i = start + t; i < end; i += 256) atomicAdd(&cnt[bindst[i]], 1);
  __syncthreads();
  const int v = cnt[t];
  ss[t] = v;
  __syncthreads();
  for (int off = 1; off < 256; off <<= 1) {
    const int add = (t >= off) ? ss[t - off] : 0;
    __syncthreads();
    ss[t] += add;
    __syncthreads();
  }
  const int excl = ss[t] - v;
  cur[t] = excl;
  const int node = (b << 8) + t;
  if (node < n_nodes) {
    deg[node] = v;
    offs[node] = start + excl;
  }
  __syncthreads();
  for (int i = start + t; i < end; i += 256) {
    const int dl = bindst[i];
    const int pos = start + atomicAdd(&cur[dl], 1);
    edgebuf[pos] = binpay[i];
  }
}

// ---------------- fused gather + skip + relu (bf16 hr), 4-deep MLP ----------------
__global__ __launch_bounds__(256) void gather_kernel(
    const bf16_t* __restrict__ hr, const int2* __restrict__ edgebuf,
    const int* __restrict__ offs, const int* __restrict__ deg,
    const float* __restrict__ skip, float* __restrict__ out,
    bf16_t* __restrict__ xbout, int n_nodes) {
  const long gid = (long)blockIdx.x * 256 + threadIdx.x;
  const int n = (int)(gid >> 4);
  if (n >= n_nodes) return;
  const int c = (int)(gid & 15) * 4;

  const int beg = offs[n];
  const int cnt = deg[n];

  float4 acc0 = {0.f, 0.f, 0.f, 0.f};
  float4 acc1 = {0.f, 0.f, 0.f, 0.f};
  int i = 0;
  for (; i + 3 < cnt; i += 4) {
    const int2 e0 = edgebuf[beg + i];
    const int2 e1 = edgebuf[beg + i + 1];
    const int2 e2 = edgebuf[beg + i + 2];
    const int2 e3 = edgebuf[beg + i + 3];
    const uint2 v0 = *reinterpret_cast<const uint2*>(
        &hr[((long)(((unsigned)e0.x) >> 27) * n_nodes + (e0.x & SRC_MASK)) * 64 + c]);
    const uint2 v1 = *reinterpret_cast<const uint2*>(
        &hr[((long)(((unsigned)e1.x) >> 27) * n_nodes + (e1.x & SRC_MASK)) * 64 + c]);
    const uint2 v2 = *reinterpret_cast<const uint2*>(
        &hr[((long)(((unsigned)e2.x) >> 27) * n_nodes + (e2.x & SRC_MASK)) * 64 + c]);
    const uint2 v3 = *reinterpret_cast<const uint2*>(
        &hr[((long)(((unsigned)e3.x) >> 27) * n_nodes + (e3.x & SRC_MASK)) * 64 + c]);
    const float n0 = __int_as_float(e0.y), n1 = __int_as_float(e1.y);
    const float n2 = __int_as_float(e2.y), n3 = __int_as_float(e3.y);
    acc0.x += bf2f(v0.x & 0xffff) * n0; acc0.y += bf2f(v0.x >> 16) * n0;
    acc0.z += bf2f(v0.y & 0xffff) * n0; acc0.w += bf2f(v0.y >> 16) * n0;
    acc1.x += bf2f(v1.x & 0xffff) * n1; acc1.y += bf2f(v1.x >> 16) * n1;
    acc1.z += bf2f(v1.y & 0xffff) * n1; acc1.w += bf2f(v1.y >> 16) * n1;
    acc0.x += bf2f(v2.x & 0xffff) * n2; acc0.y += bf2f(v2.x >> 16) * n2;
    acc0.z += bf2f(v2.y & 0xffff) * n2; acc0.w += bf2f(v2.y >> 16) * n2;
    acc1.x += bf2f(v3.x & 0xffff) * n3; acc1.y += bf2f(v3.x >> 16) * n3;
    acc1.z += bf2f(v3.y & 0xffff) * n3; acc1.w += bf2f(v3.y >> 16) * n3;
  }
  for (; i < cnt; ++i) {
    const int2 ea = edgebuf[beg + i];
    const float na = __int_as_float(ea.y);
    const uint2 va = *reinterpret_cast<const uint2*>(
        &hr[((long)(((unsigned)ea.x) >> 27) * n_nodes + (ea.x & SRC_MASK)) * 64 + c]);
    acc0.x += bf2f(va.x & 0xffff) * na; acc0.y += bf2f(va.x >> 16) * na;
    acc0.z += bf2f(va.y & 0xffff) * na; acc0.w += bf2f(va.y >> 16) * na;
  }
  float4 a;
  a.x = acc0.x + acc1.x; a.y = acc0.y + acc1.y;
  a.z = acc0.z + acc1.z; a.w = acc0.w + acc1.w;
  if (skip != nullptr) {
    const float4 s = *reinterpret_cast<const float4*>(&skip[(long)n * 64 + c]);
    a.x += s.x; a.y += s.y; a.z += s.z; a.w += s.w;
  }
  a.x = fmaxf(a.x, 0.f); a.y = fmaxf(a.y, 0.f);
  a.z = fmaxf(a.z, 0.f); a.w = fmaxf(a.w, 0.f);
  *reinterpret_cast<float4*>(&out[(long)n * 64 + c]) = a;
  if (xbout != nullptr) {
    uint2 o;
    o.x = f2bf(a.x) | (f2bf(a.y) << 16);
    o.y = f2bf(a.z) | (f2bf(a.w) << 16);
    *reinterpret_cast<uint2*>(&xbout[(long)n * 64 + c]) = o;
  }
}

// ---------------- heads ----------------
__global__ __launch_bounds__(256) void heads_kernel(
    const float* __restrict__ x, const float* __restrict__ Wa,
    const float* __restrict__ ba, const float* __restrict__ Wb,
    const float* __restrict__ bb, float* __restrict__ out, int n_nodes) {
  __shared__ float xs[64][65];
  __shared__ float wlt[64][24];  // [k][s], padded to 24
  __shared__ float bl[23];
  const int tid = threadIdx.x;
  const int base = blockIdx.x * 64;

  for (int idx = tid; idx < 2 * 64; idx += 256)
    wlt[idx & 63][idx >> 6] = Wa[idx];
  for (int idx = tid; idx < 21 * 64; idx += 256)
    wlt[idx & 63][2 + (idx >> 6)] = Wb[idx];
  if (tid < 2) bl[tid] = ba[tid];
  else if (tid < 23) bl[tid] = bb[tid - 2];
  const int nrows = min(64, n_nodes - base);
  for (int idx = tid; idx < nrows * 64; idx += 256)
    xs[idx >> 6][idx & 63] = x[(long)base * 64 + idx];
  __syncthreads();

  for (int idx = tid; idx < nrows * 23; idx += 256) {
    const int n = idx / 23;
    const int s = idx % 23;
    float acc = 0.f;
#pragma unroll
    for (int k = 0; k < 64; ++k) acc += xs[n][k] * wlt[k][s];
    acc += bl[s];
    const long node = base + n;
    if (s < 2) out[node * 2 + s] = acc;
    else out[(long)n_nodes * 2 + node * 21 + (s - 2)] = acc;
  }
}

static inline char* align_up(char* p, size_t a) {
  return (char*)(((uintptr_t)p + a - 1) & ~(uintptr_t)(a - 1));
}

extern "C" void kernel_launch(void* const* d_in, const int* in_sizes, int n_in,
                              void* d_out, int out_size, void* d_ws, size_t ws_size,
                              hipStream_t stream) {
  const float* v    = (const float*)d_in[0];
  const int*   esrc = (const int*)d_in[1];
  const int*   edst = (const int*)d_in[2];
  const int*   erel = (const int*)d_in[3];
  const float* norm = (const float*)d_in[4];
  const float* W1   = (const float*)d_in[5];
  const float* W2   = (const float*)d_in[6];
  const float* W3   = (const float*)d_in[7];
  const float* Wa   = (const float*)d_in[8];
  const float* ba   = (const float*)d_in[9];
  const float* Wb   = (const float*)d_in[10];
  const float* bb   = (const float*)d_in[11];

  const int nN = in_sizes[0] / D;  // 100000
  const int E  = in_sizes[1];      // 1200000
  const int nb = (nN + 255) >> 8;  // 256-node buckets

  // ---- workspace layout
  char* p = (char*)d_ws;
  bf16_t* hr = (bf16_t*)p;            p += 3L * nN * D * sizeof(bf16_t);
  p = align_up(p, 16);
  bf16_t* xb = (bf16_t*)p;            p += (long)nN * D * sizeof(bf16_t);
  p = align_up(p, 16);
  float* bufA = (float*)p;            p += (long)nN * D * sizeof(float);
  float* bufB = (float*)p;            p += (long)nN * D * sizeof(float);
  int* deg      = (int*)p;            p += (long)nN * sizeof(int);
  int* offs     = (int*)p;            p += (long)nN * sizeof(int);
  int* bdeg     = (int*)p;            p += (long)nb * sizeof(int);
  int* boffs    = (int*)p;            p += (long)(nb + 1) * sizeof(int);
  int* bcur     = (int*)p;            p += (long)nb * sizeof(int);
  p = align_up(p, 16);
  int2* edgebuf = (int2*)p;           p += (long)E * sizeof(int2);
  int2* binpay  = (int2*)p;           p += (long)E * sizeof(int2);
  unsigned char* bindst = (unsigned char*)p;  p += (long)E;

  const int tblocks = (nN + 63) / 64;
  const int gblocks = (int)(((long)nN * 16 + 255) / 256);
  const int hblocks = (E + ABLK - 1) / ABLK;
  const int a2blocks = (E + ABLK2 - 1) / ABLK2;
  const int cblocks = (nN * D / 4 + 255) / 256;

  // ---- CSR build (bucket-level histogram only; once per call)
  zero_kernel<<<1, 512, 0, stream>>>(bdeg, bcur, nb);
  bhist_kernel<<<hblocks, ATHR, 0, stream>>>(edst, bdeg, E, nb);
  bscan_kernel<<<1, 512, 0, stream>>>(bdeg, boffs, nb);
  binA_kernel<<<a2blocks, ATHR, 0, stream>>>(esrc, edst, erel, norm, boffs, bcur,
                                             binpay, bindst, E, nb);
  binB_kernel<<<nb, 256, 0, stream>>>(binpay, bindst, boffs, edgebuf, deg, offs, nN);

  // ---- layer 1: v -> bufA (no skip); xb = bf16(v)
  conv_kernel<<<cblocks, 256, 0, stream>>>(v, xb, nN * D / 4);
  transform_kernel<<<tblocks, 256, 0, stream>>>(xb, W1, hr, nN);
  gather_kernel<<<gblocks, 256, 0, stream>>>(hr, edgebuf, offs, deg, nullptr,
                                             bufA, xb, nN);

  // ---- layer 2: bufA -> bufB (skip); xb = bf16(bufB)
  transform_kernel<<<tblocks, 256, 0, stream>>>(xb, W2, hr, nN);
  gather_kernel<<<gblocks, 256, 0, stream>>>(hr, edgebuf, offs, deg, bufA,
                                             bufB, xb, nN);

  // ---- layer 3: bufB -> bufA (skip); final (no xb needed)
  transform_kernel<<<tblocks, 256, 0, stream>>>(xb, W3, hr, nN);
  gather_kernel<<<gblocks, 256, 0, stream>>>(hr, edgebuf, offs, deg, bufB,
                                             bufA, nullptr, nN);

  // ---- heads
  heads_kernel<<<tblocks, 256, 0, stream>>>(bufA, Wa, ba, Wb, bb, (float*)d_out, nN);
}

// Round 15
// 269.933 us; speedup vs baseline: 1.0496x; 1.0496x over previous
//
#include <hip/hip_runtime.h>

#define D 64
#define NREL 3
#define SRC_MASK 0x07FFFFFF
#define ATHR 512
#define APT 8
#define ABLK (ATHR * APT)  // 4096 edges per block (bhist, binA)

typedef unsigned short bf16_t;
typedef __attribute__((ext_vector_type(8))) short short8v;   // 8 bf16 = 4 VGPRs
typedef __attribute__((ext_vector_type(4))) float float4v;

__device__ __forceinline__ float bf2f(unsigned int u16) {
  return __uint_as_float(u16 << 16);
}
__device__ __forceinline__ unsigned int f2bf(float f) {
  unsigned int x = __float_as_uint(f);
  return (x + 0x7fffu + ((x >> 16) & 1u)) >> 16;  // round-to-nearest-even
}

// ---------------- tiny zero (R12-verified: replaces 2x ~40us fill dispatches) ----
__global__ __launch_bounds__(512) void zero_kernel(int* __restrict__ a,
                                                   int* __restrict__ b, int n) {
  const int t = threadIdx.x;
  for (int i = t; i < n; i += 512) { a[i] = 0; b[i] = 0; }
}

// ---------------- f32 -> bf16 convert (for layer-1 input) ----------------
__global__ __launch_bounds__(256) void conv_kernel(
    const float* __restrict__ in, bf16_t* __restrict__ out, int n4) {
  const int i = blockIdx.x * 256 + threadIdx.x;
  if (i >= n4) return;
  const float4 f = reinterpret_cast<const float4*>(in)[i];
  uint2 o;
  o.x = f2bf(f.x) | (f2bf(f.y) << 16);
  o.y = f2bf(f.z) | (f2bf(f.w) << 16);
  reinterpret_cast<uint2*>(out)[i] = o;
}

// ---------------- transform via MFMA (R11-verified: 4x faster than VALU) ----------
__global__ __launch_bounds__(256) void transform_kernel(
    const bf16_t* __restrict__ xb, const float* __restrict__ W,
    bf16_t* __restrict__ hr, int n_nodes) {
  __shared__ bf16_t wt[NREL * 64 * 72];  // 27.6 KB
  const int tid = threadIdx.x;

  for (int idx = tid; idx < NREL * 64 * 64; idx += 256) {
    const int r = idx >> 12;
    const int k = (idx >> 6) & 63;
    const int od = idx & 63;
    wt[(r * 64 + od) * 72 + k] = (bf16_t)f2bf(W[idx]);
  }
  __syncthreads();

  const int wid = tid >> 6;
  const int lane = tid & 63;
  const int n0 = blockIdx.x * 64 + wid * 16;
  if (n0 >= n_nodes) return;

  const bf16_t* xrow = &xb[(long)(n0 + (lane & 15)) * 64 + (lane >> 4) * 8];
  const short8v bx0 = *reinterpret_cast<const short8v*>(xrow);
  const short8v bx1 = *reinterpret_cast<const short8v*>(xrow + 32);

  const int node = n0 + (lane & 15);
#pragma unroll
  for (int r = 0; r < NREL; ++r) {
#pragma unroll
    for (int t = 0; t < 4; ++t) {
      const bf16_t* wrow =
          &wt[(r * 64 + t * 16 + (lane & 15)) * 72 + (lane >> 4) * 8];
      const short8v a0 = *reinterpret_cast<const short8v*>(wrow);
      const short8v a1 = *reinterpret_cast<const short8v*>(wrow + 32);
      float4v acc = {0.f, 0.f, 0.f, 0.f};
      acc = __builtin_amdgcn_mfma_f32_16x16x32_bf16(a0, bx0, acc, 0, 0, 0);
      acc = __builtin_amdgcn_mfma_f32_16x16x32_bf16(a1, bx1, acc, 0, 0, 0);
      const int od = t * 16 + (lane >> 4) * 4;
      uint2 o;
      o.x = f2bf(acc[0]) | (f2bf(acc[1]) << 16);
      o.y = f2bf(acc[2]) | (f2bf(acc[3]) << 16);
      *reinterpret_cast<uint2*>(&hr[((long)r * n_nodes + node) * 64 + od]) = o;
    }
  }
}

// ---------------- CSR build (bucket-level only; no node-level atomics) ----------
__global__ __launch_bounds__(ATHR) void bhist_kernel(
    const int* __restrict__ dst, int* __restrict__ bdeg, int n_edges, int nb) {
  __shared__ int cnt[400];
  const int t = threadIdx.x;
  for (int b = t; b < nb; b += ATHR) cnt[b] = 0;
  __syncthreads();
  const long e0 = (long)blockIdx.x * ABLK;
#pragma unroll
  for (int i = 0; i < APT; ++i) {
    const long e = e0 + t + (long)i * ATHR;
    if (e < n_edges) atomicAdd(&cnt[dst[e] >> 8], 1);
  }
  __syncthreads();
  for (int b = t; b < nb; b += ATHR)
    if (cnt[b]) atomicAdd(&bdeg[b], cnt[b]);
}

// Single block: exclusive scan of bdeg[nb] -> boffs[nb+1] (nb <= 512).
__global__ __launch_bounds__(512) void bscan_kernel(
    const int* __restrict__ bdeg, int* __restrict__ boffs, int nb) {
  __shared__ int s[512];
  const int t = threadIdx.x;
  const int v = (t < nb) ? bdeg[t] : 0;
  s[t] = v;
  __syncthreads();
  for (int off = 1; off < 512; off <<= 1) {
    const int add = (t >= off) ? s[t - off] : 0;
    __syncthreads();
    s[t] += add;
    __syncthreads();
  }
  if (t < nb) boffs[t] = s[t] - v;
  if (t == 511) boffs[nb] = s[nb - 1];
}

// Phase A (one-pass, 4096 edges/block — R12-verified 42us; R13's 16K-edge
// two-pass variant dropped occupancy to 5% and regressed to 62us).
__global__ __launch_bounds__(ATHR) void binA_kernel(
    const int* __restrict__ src, const int* __restrict__ dst,
    const int* __restrict__ rel, const float* __restrict__ norm,
    const int* __restrict__ boffs, int* __restrict__ bcur,
    int2* __restrict__ binpay, unsigned char* __restrict__ bindst,
    int n_edges, int nb) {
  __shared__ int cnt[400];
  __shared__ int basea[400];
  const int t = threadIdx.x;
  const long e0 = (long)blockIdx.x * ABLK;

  for (int b = t; b < nb; b += ATHR) cnt[b] = 0;
  __syncthreads();

  int2 pay[APT];
  int bk[APT], slot[APT], dlo[APT];
#pragma unroll
  for (int i = 0; i < APT; ++i) {
    const long e = e0 + t + (long)i * ATHR;
    if (e < n_edges) {
      const int d = dst[e];
      bk[i] = d >> 8;
      dlo[i] = d & 255;
      pay[i] = make_int2(src[e] | (rel[e] << 27), __float_as_int(norm[e]));
      slot[i] = atomicAdd(&cnt[bk[i]], 1);
    } else {
      bk[i] = -1;
    }
  }
  __syncthreads();

  for (int b = t; b < nb; b += ATHR) {
    const int c = cnt[b];
    basea[b] = c ? (boffs[b] + atomicAdd(&bcur[b], c)) : 0;
  }
  __syncthreads();

#pragma unroll
  for (int i = 0; i < APT; ++i) {
    if (bk[i] >= 0) {
      const int pos = basea[bk[i]] + slot[i];
      binpay[pos] = pay[i];
      bindst[pos] = (unsigned char)dlo[i];
    }
  }
}

// Phase B: one block per bucket. Pass 1: count per-node edges in LDS, LDS
// exclusive scan -> write deg/offs to global. Pass 2: place edges at exact
// CSR position via LDS cursors. No global atomics.
__global__ __launch_bounds__(256) void binB_kernel(
    const int2* __restrict__ binpay, const unsigned char* __restrict__ bindst,
    const int* __restrict__ boffs, int2* __restrict__ edgebuf,
    int* __restrict__ deg, int* __restrict__ offs, int n_nodes) {
  __shared__ int cnt[256];
  __shared__ int ss[256];
  __shared__ int cur[256];
  const int b = blockIdx.x;
  const int t = threadIdx.x;
  cnt[t] = 0;
  __syncthreads();
  const int start = boffs[b];
  const int end = boffs[b + 1];
  for (int i = start + t; i < end; i += 256) atomicAdd(&cnt[bindst[i]], 1);
  __syncthreads();
  const int v = cnt[t];
  ss[t] = v;
  __syncthreads();
  for (int off = 1; off < 256; off <<= 1) {
    const int add = (t >= off) ? ss[t - off] : 0;
    __syncthreads();
    ss[t] += add;
    __syncthreads();
  }
  const int excl = ss[t] - v;
  cur[t] = excl;
  const int node = (b << 8) + t;
  if (node < n_nodes) {
    deg[node] = v;
    offs[node] = start + excl;
  }
  __syncthreads();
  for (int i = start + t; i < end; i += 256) {
    const int dl = bindst[i];
    const int pos = start + atomicAdd(&cur[dl], 1);
    edgebuf[pos] = binpay[i];
  }
}

// ---------------- fused gather + skip + relu: 8 threads/node, uint4 hr reads ----
// 16B/lane (coalescing sweet spot) halves wave-instructions per edge vs the
// 16-thread/uint2 version; 4-edge MLP unroll unchanged.
__global__ __launch_bounds__(256) void gather_kernel(
    const bf16_t* __restrict__ hr, const int2* __restrict__ edgebuf,
    const int* __restrict__ offs, const int* __restrict__ deg,
    const float* __restrict__ skip, float* __restrict__ out,
    bf16_t* __restrict__ xbout, int n_nodes) {
  const long gid = (long)blockIdx.x * 256 + threadIdx.x;
  const int n = (int)(gid >> 3);
  if (n >= n_nodes) return;
  const int c = (int)(gid & 7) * 8;  // 8 features per thread

  const int beg = offs[n];
  const int cnt = deg[n];

  float acc0[8], acc1[8];
#pragma unroll
  for (int j = 0; j < 8; ++j) { acc0[j] = 0.f; acc1[j] = 0.f; }

  int i = 0;
  for (; i + 3 < cnt; i += 4) {
    const int2 e0 = edgebuf[beg + i];
    const int2 e1 = edgebuf[beg + i + 1];
    const int2 e2 = edgebuf[beg + i + 2];
    const int2 e3 = edgebuf[beg + i + 3];
    const uint4 v0 = *reinterpret_cast<const uint4*>(
        &hr[((long)(((unsigned)e0.x) >> 27) * n_nodes + (e0.x & SRC_MASK)) * 64 + c]);
    const uint4 v1 = *reinterpret_cast<const uint4*>(
        &hr[((long)(((unsigned)e1.x) >> 27) * n_nodes + (e1.x & SRC_MASK)) * 64 + c]);
    const uint4 v2 = *reinterpret_cast<const uint4*>(
        &hr[((long)(((unsigned)e2.x) >> 27) * n_nodes + (e2.x & SRC_MASK)) * 64 + c]);
    const uint4 v3 = *reinterpret_cast<const uint4*>(
        &hr[((long)(((unsigned)e3.x) >> 27) * n_nodes + (e3.x & SRC_MASK)) * 64 + c]);
    const float n0 = __int_as_float(e0.y), n1 = __int_as_float(e1.y);
    const float n2 = __int_as_float(e2.y), n3 = __int_as_float(e3.y);
    const unsigned int w0[4] = {v0.x, v0.y, v0.z, v0.w};
    const unsigned int w1[4] = {v1.x, v1.y, v1.z, v1.w};
    const unsigned int w2[4] = {v2.x, v2.y, v2.z, v2.w};
    const unsigned int w3[4] = {v3.x, v3.y, v3.z, v3.w};
#pragma unroll
    for (int j = 0; j < 4; ++j) {
      acc0[2 * j + 0] += bf2f(w0[j] & 0xffff) * n0;
      acc0[2 * j + 1] += bf2f(w0[j] >> 16) * n0;
      acc1[2 * j + 0] += bf2f(w1[j] & 0xffff) * n1;
      acc1[2 * j + 1] += bf2f(w1[j] >> 16) * n1;
      acc0[2 * j + 0] += bf2f(w2[j] & 0xffff) * n2;
      acc0[2 * j + 1] += bf2f(w2[j] >> 16) * n2;
      acc1[2 * j + 0] += bf2f(w3[j] & 0xffff) * n3;
      acc1[2 * j + 1] += bf2f(w3[j] >> 16) * n3;
    }
  }
  for (; i < cnt; ++i) {
    const int2 ea = edgebuf[beg + i];
    const float na = __int_as_float(ea.y);
    const uint4 va = *reinterpret_cast<const uint4*>(
        &hr[((long)(((unsigned)ea.x) >> 27) * n_nodes + (ea.x & SRC_MASK)) * 64 + c]);
    const unsigned int wa[4] = {va.x, va.y, va.z, va.w};
#pragma unroll
    for (int j = 0; j < 4; ++j) {
      acc0[2 * j + 0] += bf2f(wa[j] & 0xffff) * na;
      acc0[2 * j + 1] += bf2f(wa[j] >> 16) * na;
    }
  }

  float a[8];
#pragma unroll
  for (int j = 0; j < 8; ++j) a[j] = acc0[j] + acc1[j];
  if (skip != nullptr) {
    const float4 s0 = *reinterpret_cast<const float4*>(&skip[(long)n * 64 + c]);
    const float4 s1 = *reinterpret_cast<const float4*>(&skip[(long)n * 64 + c + 4]);
    a[0] += s0.x; a[1] += s0.y; a[2] += s0.z; a[3] += s0.w;
    a[4] += s1.x; a[5] += s1.y; a[6] += s1.z; a[7] += s1.w;
  }
#pragma unroll
  for (int j = 0; j < 8; ++j) a[j] = fmaxf(a[j], 0.f);
  float4 o0 = {a[0], a[1], a[2], a[3]};
  float4 o1 = {a[4], a[5], a[6], a[7]};
  *reinterpret_cast<float4*>(&out[(long)n * 64 + c]) = o0;
  *reinterpret_cast<float4*>(&out[(long)n * 64 + c + 4]) = o1;
  if (xbout != nullptr) {
    uint4 ob;
    ob.x = f2bf(a[0]) | (f2bf(a[1]) << 16);
    ob.y = f2bf(a[2]) | (f2bf(a[3]) << 16);
    ob.z = f2bf(a[4]) | (f2bf(a[5]) << 16);
    ob.w = f2bf(a[6]) | (f2bf(a[7]) << 16);
    *reinterpret_cast<uint4*>(&xbout[(long)n * 64 + c]) = ob;
  }
}

// ---------------- heads ----------------
__global__ __launch_bounds__(256) void heads_kernel(
    const float* __restrict__ x, const float* __restrict__ Wa,
    const float* __restrict__ ba, const float* __restrict__ Wb,
    const float* __restrict__ bb, float* __restrict__ out, int n_nodes) {
  __shared__ float xs[64][65];
  __shared__ float wlt[64][24];  // [k][s], padded to 24
  __shared__ float bl[23];
  const int tid = threadIdx.x;
  const int base = blockIdx.x * 64;

  for (int idx = tid; idx < 2 * 64; idx += 256)
    wlt[idx & 63][idx >> 6] = Wa[idx];
  for (int idx = tid; idx < 21 * 64; idx += 256)
    wlt[idx & 63][2 + (idx >> 6)] = Wb[idx];
  if (tid < 2) bl[tid] = ba[tid];
  else if (tid < 23) bl[tid] = bb[tid - 2];
  const int nrows = min(64, n_nodes - base);
  for (int idx = tid; idx < nrows * 64; idx += 256)
    xs[idx >> 6][idx & 63] = x[(long)base * 64 + idx];
  __syncthreads();

  for (int idx = tid; idx < nrows * 23; idx += 256) {
    const int n = idx / 23;
    const int s = idx % 23;
    float acc = 0.f;
#pragma unroll
    for (int k = 0; k < 64; ++k) acc += xs[n][k] * wlt[k][s];
    acc += bl[s];
    const long node = base + n;
    if (s < 2) out[node * 2 + s] = acc;
    else out[(long)n_nodes * 2 + node * 21 + (s - 2)] = acc;
  }
}

static inline char* align_up(char* p, size_t a) {
  return (char*)(((uintptr_t)p + a - 1) & ~(uintptr_t)(a - 1));
}

extern "C" void kernel_launch(void* const* d_in, const int* in_sizes, int n_in,
                              void* d_out, int out_size, void* d_ws, size_t ws_size,
                              hipStream_t stream) {
  const float* v    = (const float*)d_in[0];
  const int*   esrc = (const int*)d_in[1];
  const int*   edst = (const int*)d_in[2];
  const int*   erel = (const int*)d_in[3];
  const float* norm = (const float*)d_in[4];
  const float* W1   = (const float*)d_in[5];
  const float* W2   = (const float*)d_in[6];
  const float* W3   = (const float*)d_in[7];
  const float* Wa   = (const float*)d_in[8];
  const float* ba   = (const float*)d_in[9];
  const float* Wb   = (const float*)d_in[10];
  const float* bb   = (const float*)d_in[11];

  const int nN = in_sizes[0] / D;  // 100000
  const int E  = in_sizes[1];      // 1200000
  const int nb = (nN + 255) >> 8;  // 256-node buckets

  // ---- workspace layout
  char* p = (char*)d_ws;
  bf16_t* hr = (bf16_t*)p;            p += 3L * nN * D * sizeof(bf16_t);
  p = align_up(p, 16);
  bf16_t* xb = (bf16_t*)p;            p += (long)nN * D * sizeof(bf16_t);
  p = align_up(p, 16);
  float* bufA = (float*)p;            p += (long)nN * D * sizeof(float);
  float* bufB = (float*)p;            p += (long)nN * D * sizeof(float);
  int* deg      = (int*)p;            p += (long)nN * sizeof(int);
  int* offs     = (int*)p;            p += (long)nN * sizeof(int);
  int* bdeg     = (int*)p;            p += (long)nb * sizeof(int);
  int* boffs    = (int*)p;            p += (long)(nb + 1) * sizeof(int);
  int* bcur     = (int*)p;            p += (long)nb * sizeof(int);
  p = align_up(p, 16);
  int2* edgebuf = (int2*)p;           p += (long)E * sizeof(int2);
  int2* binpay  = (int2*)p;           p += (long)E * sizeof(int2);
  unsigned char* bindst = (unsigned char*)p;  p += (long)E;

  const int tblocks = (nN + 63) / 64;
  const int gblocks = (int)(((long)nN * 8 + 255) / 256);
  const int hblocks = (E + ABLK - 1) / ABLK;
  const int cblocks = (nN * D / 4 + 255) / 256;

  // ---- CSR build (bucket-level histogram only; once per call)
  zero_kernel<<<1, 512, 0, stream>>>(bdeg, bcur, nb);
  bhist_kernel<<<hblocks, ATHR, 0, stream>>>(edst, bdeg, E, nb);
  bscan_kernel<<<1, 512, 0, stream>>>(bdeg, boffs, nb);
  binA_kernel<<<hblocks, ATHR, 0, stream>>>(esrc, edst, erel, norm, boffs, bcur,
                                            binpay, bindst, E, nb);
  binB_kernel<<<nb, 256, 0, stream>>>(binpay, bindst, boffs, edgebuf, deg, offs, nN);

  // ---- layer 1: v -> bufA (no skip); xb = bf16(v)
  conv_kernel<<<cblocks, 256, 0, stream>>>(v, xb, nN * D / 4);
  transform_kernel<<<tblocks, 256, 0, stream>>>(xb, W1, hr, nN);
  gather_kernel<<<gblocks, 256, 0, stream>>>(hr, edgebuf, offs, deg, nullptr,
                                             bufA, xb, nN);

  // ---- layer 2: bufA -> bufB (skip); xb = bf16(bufB)
  transform_kernel<<<tblocks, 256, 0, stream>>>(xb, W2, hr, nN);
  gather_kernel<<<gblocks, 256, 0, stream>>>(hr, edgebuf, offs, deg, bufA,
                                             bufB, xb, nN);

  // ---- layer 3: bufB -> bufA (skip); final (no xb needed)
  transform_kernel<<<tblocks, 256, 0, stream>>>(xb, W3, hr, nN);
  gather_kernel<<<gblocks, 256, 0, stream>>>(hr, edgebuf, offs, deg, bufB,
                                             bufA, nullptr, nN);

  // ---- heads
  heads_kernel<<<tblocks, 256, 0, stream>>>(bufA, Wa, ba, Wb, bb, (float*)d_out, nN);
}

// Round 16
// 262.460 us; speedup vs baseline: 1.0795x; 1.0285x over previous
//
#include <hip/hip_runtime.h>

#define D 64
#define NREL 3
#define SRC_MASK 0x1FFFF      // 17 bits: N=100000 < 2^17
#define ATHR 512
#define APT 8
#define ABLK (ATHR * APT)     // 4096 edges per block (bhist, binA)
#define BSH 9                 // 512-node buckets
#define BSZ 512

typedef unsigned short bf16_t;
typedef __attribute__((ext_vector_type(8))) short short8v;   // 8 bf16 = 4 VGPRs
typedef __attribute__((ext_vector_type(4))) float float4v;

__device__ __forceinline__ float bf2f(unsigned int u16) {
  return __uint_as_float(u16 << 16);
}
__device__ __forceinline__ unsigned int f2bf(float f) {
  unsigned int x = __float_as_uint(f);
  return (x + 0x7fffu + ((x >> 16) & 1u)) >> 16;  // round-to-nearest-even
}

// ---------------- tiny zero (R12-verified: replaces 2x ~40us fill dispatches) ----
__global__ __launch_bounds__(512) void zero_kernel(int* __restrict__ a,
                                                   int* __restrict__ b, int n) {
  const int t = threadIdx.x;
  for (int i = t; i < n; i += 512) { a[i] = 0; b[i] = 0; }
}

// ---------------- f32 -> bf16 convert (for layer-1 input) ----------------
__global__ __launch_bounds__(256) void conv_kernel(
    const float* __restrict__ in, bf16_t* __restrict__ out, int n4) {
  const int i = blockIdx.x * 256 + threadIdx.x;
  if (i >= n4) return;
  const float4 f = reinterpret_cast<const float4*>(in)[i];
  uint2 o;
  o.x = f2bf(f.x) | (f2bf(f.y) << 16);
  o.y = f2bf(f.z) | (f2bf(f.w) << 16);
  reinterpret_cast<uint2*>(out)[i] = o;
}

// ---------------- transform via MFMA (R11-verified: 4x faster than VALU) ----------
__global__ __launch_bounds__(256) void transform_kernel(
    const bf16_t* __restrict__ xb, const float* __restrict__ W,
    bf16_t* __restrict__ hr, int n_nodes) {
  __shared__ bf16_t wt[NREL * 64 * 72];  // 27.6 KB
  const int tid = threadIdx.x;

  for (int idx = tid; idx < NREL * 64 * 64; idx += 256) {
    const int r = idx >> 12;
    const int k = (idx >> 6) & 63;
    const int od = idx & 63;
    wt[(r * 64 + od) * 72 + k] = (bf16_t)f2bf(W[idx]);
  }
  __syncthreads();

  const int wid = tid >> 6;
  const int lane = tid & 63;
  const int n0 = blockIdx.x * 64 + wid * 16;
  if (n0 >= n_nodes) return;

  const bf16_t* xrow = &xb[(long)(n0 + (lane & 15)) * 64 + (lane >> 4) * 8];
  const short8v bx0 = *reinterpret_cast<const short8v*>(xrow);
  const short8v bx1 = *reinterpret_cast<const short8v*>(xrow + 32);

  const int node = n0 + (lane & 15);
#pragma unroll
  for (int r = 0; r < NREL; ++r) {
#pragma unroll
    for (int t = 0; t < 4; ++t) {
      const bf16_t* wrow =
          &wt[(r * 64 + t * 16 + (lane & 15)) * 72 + (lane >> 4) * 8];
      const short8v a0 = *reinterpret_cast<const short8v*>(wrow);
      const short8v a1 = *reinterpret_cast<const short8v*>(wrow + 32);
      float4v acc = {0.f, 0.f, 0.f, 0.f};
      acc = __builtin_amdgcn_mfma_f32_16x16x32_bf16(a0, bx0, acc, 0, 0, 0);
      acc = __builtin_amdgcn_mfma_f32_16x16x32_bf16(a1, bx1, acc, 0, 0, 0);
      const int od = t * 16 + (lane >> 4) * 4;
      uint2 o;
      o.x = f2bf(acc[0]) | (f2bf(acc[1]) << 16);
      o.y = f2bf(acc[2]) | (f2bf(acc[3]) << 16);
      *reinterpret_cast<uint2*>(&hr[((long)r * n_nodes + node) * 64 + od]) = o;
    }
  }
}

// ---------------- CSR build (bucket-level only; no node-level atomics) ----------
__global__ __launch_bounds__(ATHR) void bhist_kernel(
    const int* __restrict__ dst, int* __restrict__ bdeg, int n_edges, int nb) {
  __shared__ int cnt[200];
  const int t = threadIdx.x;
  for (int b = t; b < nb; b += ATHR) cnt[b] = 0;
  __syncthreads();
  const long e0 = (long)blockIdx.x * ABLK;
#pragma unroll
  for (int i = 0; i < APT; ++i) {
    const long e = e0 + t + (long)i * ATHR;
    if (e < n_edges) atomicAdd(&cnt[dst[e] >> BSH], 1);
  }
  __syncthreads();
  for (int b = t; b < nb; b += ATHR)
    if (cnt[b]) atomicAdd(&bdeg[b], cnt[b]);
}

// Single block: exclusive scan of bdeg[nb] -> boffs[nb+1] (nb <= 512).
__global__ __launch_bounds__(512) void bscan_kernel(
    const int* __restrict__ bdeg, int* __restrict__ boffs, int nb) {
  __shared__ int s[512];
  const int t = threadIdx.x;
  const int v = (t < nb) ? bdeg[t] : 0;
  s[t] = v;
  __syncthreads();
  for (int off = 1; off < 512; off <<= 1) {
    const int add = (t >= off) ? s[t - off] : 0;
    __syncthreads();
    s[t] += add;
    __syncthreads();
  }
  if (t < nb) boffs[t] = s[t] - v;
  if (t == 511) boffs[nb] = s[nb - 1];
}

// Phase A (one-pass, 4096 edges/block — R15-verified 42us at 19% occupancy;
// 16K-edge two-pass variant regressed to 62us at 5% occ, R13).
// Payload packs src(17b) | rel(2b) | node-in-bucket(9b) into pay.x -> no
// separate bindst byte array (worst write-amp component in R15: 30MB total).
__global__ __launch_bounds__(ATHR) void binA_kernel(
    const int* __restrict__ src, const int* __restrict__ dst,
    const int* __restrict__ rel, const float* __restrict__ norm,
    const int* __restrict__ boffs, int* __restrict__ bcur,
    int2* __restrict__ binpay, int n_edges, int nb) {
  __shared__ int cnt[200];
  __shared__ int basea[200];
  const int t = threadIdx.x;
  const long e0 = (long)blockIdx.x * ABLK;

  for (int b = t; b < nb; b += ATHR) cnt[b] = 0;
  __syncthreads();

  int2 pay[APT];
  int bk[APT], slot[APT];
#pragma unroll
  for (int i = 0; i < APT; ++i) {
    const long e = e0 + t + (long)i * ATHR;
    if (e < n_edges) {
      const int d = dst[e];
      bk[i] = d >> BSH;
      pay[i] = make_int2(src[e] | (rel[e] << 17) | ((d & (BSZ - 1)) << 19),
                         __float_as_int(norm[e]));
      slot[i] = atomicAdd(&cnt[bk[i]], 1);
    } else {
      bk[i] = -1;
    }
  }
  __syncthreads();

  for (int b = t; b < nb; b += ATHR) {
    const int c = cnt[b];
    basea[b] = c ? (boffs[b] + atomicAdd(&bcur[b], c)) : 0;
  }
  __syncthreads();

#pragma unroll
  for (int i = 0; i < APT; ++i) {
    if (bk[i] >= 0) binpay[basea[bk[i]] + slot[i]] = pay[i];
  }
}

// Phase B: one 512-thread block per 512-node bucket. Pass 1: count per-node
// edges in LDS, LDS exclusive scan -> write deg/offs to global. Pass 2: place
// edges at exact CSR position via LDS cursors. No global atomics.
__global__ __launch_bounds__(512) void binB_kernel(
    const int2* __restrict__ binpay, const int* __restrict__ boffs,
    int2* __restrict__ edgebuf, int* __restrict__ deg, int* __restrict__ offs,
    int n_nodes) {
  __shared__ int cnt[512];
  __shared__ int ss[512];
  __shared__ int cur[512];
  const int b = blockIdx.x;
  const int t = threadIdx.x;
  cnt[t] = 0;
  __syncthreads();
  const int start = boffs[b];
  const int end = boffs[b + 1];
  for (int i = start + t; i < end; i += 512)
    atomicAdd(&cnt[((unsigned)binpay[i].x >> 19) & (BSZ - 1)], 1);
  __syncthreads();
  const int v = cnt[t];
  ss[t] = v;
  __syncthreads();
  for (int off = 1; off < 512; off <<= 1) {
    const int add = (t >= off) ? ss[t - off] : 0;
    __syncthreads();
    ss[t] += add;
    __syncthreads();
  }
  const int excl = ss[t] - v;
  cur[t] = excl;
  const int node = (b << BSH) + t;
  if (node < n_nodes) {
    deg[node] = v;
    offs[node] = start + excl;
  }
  __syncthreads();
  for (int i = start + t; i < end; i += 512) {
    const int2 pay = binpay[i];
    const int dl = ((unsigned)pay.x >> 19) & (BSZ - 1);
    const int pos = start + atomicAdd(&cur[dl], 1);
    edgebuf[pos] = pay;
  }
}

// ---------------- fused gather + skip + relu: 8 threads/node, uint4 hr reads ----
__global__ __launch_bounds__(256) void gather_kernel(
    const bf16_t* __restrict__ hr, const int2* __restrict__ edgebuf,
    const int* __restrict__ offs, const int* __restrict__ deg,
    const float* __restrict__ skip, float* __restrict__ out,
    bf16_t* __restrict__ xbout, int n_nodes) {
  const long gid = (long)blockIdx.x * 256 + threadIdx.x;
  const int n = (int)(gid >> 3);
  if (n >= n_nodes) return;
  const int c = (int)(gid & 7) * 8;  // 8 features per thread

  const int beg = offs[n];
  const int cnt = deg[n];

  float acc0[8], acc1[8];
#pragma unroll
  for (int j = 0; j < 8; ++j) { acc0[j] = 0.f; acc1[j] = 0.f; }

  int i = 0;
  for (; i + 3 < cnt; i += 4) {
    const int2 e0 = edgebuf[beg + i];
    const int2 e1 = edgebuf[beg + i + 1];
    const int2 e2 = edgebuf[beg + i + 2];
    const int2 e3 = edgebuf[beg + i + 3];
    const uint4 v0 = *reinterpret_cast<const uint4*>(
        &hr[((long)((((unsigned)e0.x) >> 17) & 3) * n_nodes + (e0.x & SRC_MASK)) * 64 + c]);
    const uint4 v1 = *reinterpret_cast<const uint4*>(
        &hr[((long)((((unsigned)e1.x) >> 17) & 3) * n_nodes + (e1.x & SRC_MASK)) * 64 + c]);
    const uint4 v2 = *reinterpret_cast<const uint4*>(
        &hr[((long)((((unsigned)e2.x) >> 17) & 3) * n_nodes + (e2.x & SRC_MASK)) * 64 + c]);
    const uint4 v3 = *reinterpret_cast<const uint4*>(
        &hr[((long)((((unsigned)e3.x) >> 17) & 3) * n_nodes + (e3.x & SRC_MASK)) * 64 + c]);
    const float n0 = __int_as_float(e0.y), n1 = __int_as_float(e1.y);
    const float n2 = __int_as_float(e2.y), n3 = __int_as_float(e3.y);
    const unsigned int w0[4] = {v0.x, v0.y, v0.z, v0.w};
    const unsigned int w1[4] = {v1.x, v1.y, v1.z, v1.w};
    const unsigned int w2[4] = {v2.x, v2.y, v2.z, v2.w};
    const unsigned int w3[4] = {v3.x, v3.y, v3.z, v3.w};
#pragma unroll
    for (int j = 0; j < 4; ++j) {
      acc0[2 * j + 0] += bf2f(w0[j] & 0xffff) * n0;
      acc0[2 * j + 1] += bf2f(w0[j] >> 16) * n0;
      acc1[2 * j + 0] += bf2f(w1[j] & 0xffff) * n1;
      acc1[2 * j + 1] += bf2f(w1[j] >> 16) * n1;
      acc0[2 * j + 0] += bf2f(w2[j] & 0xffff) * n2;
      acc0[2 * j + 1] += bf2f(w2[j] >> 16) * n2;
      acc1[2 * j + 0] += bf2f(w3[j] & 0xffff) * n3;
      acc1[2 * j + 1] += bf2f(w3[j] >> 16) * n3;
    }
  }
  for (; i < cnt; ++i) {
    const int2 ea = edgebuf[beg + i];
    const float na = __int_as_float(ea.y);
    const uint4 va = *reinterpret_cast<const uint4*>(
        &hr[((long)((((unsigned)ea.x) >> 17) & 3) * n_nodes + (ea.x & SRC_MASK)) * 64 + c]);
    const unsigned int wa[4] = {va.x, va.y, va.z, va.w};
#pragma unroll
    for (int j = 0; j < 4; ++j) {
      acc0[2 * j + 0] += bf2f(wa[j] & 0xffff) * na;
      acc0[2 * j + 1] += bf2f(wa[j] >> 16) * na;
    }
  }

  float a[8];
#pragma unroll
  for (int j = 0; j < 8; ++j) a[j] = acc0[j] + acc1[j];
  if (skip != nullptr) {
    const float4 s0 = *reinterpret_cast<const float4*>(&skip[(long)n * 64 + c]);
    const float4 s1 = *reinterpret_cast<const float4*>(&skip[(long)n * 64 + c + 4]);
    a[0] += s0.x; a[1] += s0.y; a[2] += s0.z; a[3] += s0.w;
    a[4] += s1.x; a[5] += s1.y; a[6] += s1.z; a[7] += s1.w;
  }
#pragma unroll
  for (int j = 0; j < 8; ++j) a[j] = fmaxf(a[j], 0.f);
  float4 o0 = {a[0], a[1], a[2], a[3]};
  float4 o1 = {a[4], a[5], a[6], a[7]};
  *reinterpret_cast<float4*>(&out[(long)n * 64 + c]) = o0;
  *reinterpret_cast<float4*>(&out[(long)n * 64 + c + 4]) = o1;
  if (xbout != nullptr) {
    uint4 ob;
    ob.x = f2bf(a[0]) | (f2bf(a[1]) << 16);
    ob.y = f2bf(a[2]) | (f2bf(a[3]) << 16);
    ob.z = f2bf(a[4]) | (f2bf(a[5]) << 16);
    ob.w = f2bf(a[6]) | (f2bf(a[7]) << 16);
    *reinterpret_cast<uint4*>(&xbout[(long)n * 64 + c]) = ob;
  }
}

// ---------------- heads ----------------
__global__ __launch_bounds__(256) void heads_kernel(
    const float* __restrict__ x, const float* __restrict__ Wa,
    const float* __restrict__ ba, const float* __restrict__ Wb,
    const float* __restrict__ bb, float* __restrict__ out, int n_nodes) {
  __shared__ float xs[64][65];
  __shared__ float wlt[64][24];  // [k][s], padded to 24
  __shared__ float bl[23];
  const int tid = threadIdx.x;
  const int base = blockIdx.x * 64;

  for (int idx = tid; idx < 2 * 64; idx += 256)
    wlt[idx & 63][idx >> 6] = Wa[idx];
  for (int idx = tid; idx < 21 * 64; idx += 256)
    wlt[idx & 63][2 + (idx >> 6)] = Wb[idx];
  if (tid < 2) bl[tid] = ba[tid];
  else if (tid < 23) bl[tid] = bb[tid - 2];
  const int nrows = min(64, n_nodes - base);
  for (int idx = tid; idx < nrows * 64; idx += 256)
    xs[idx >> 6][idx & 63] = x[(long)base * 64 + idx];
  __syncthreads();

  for (int idx = tid; idx < nrows * 23; idx += 256) {
    const int n = idx / 23;
    const int s = idx % 23;
    float acc = 0.f;
#pragma unroll
    for (int k = 0; k < 64; ++k) acc += xs[n][k] * wlt[k][s];
    acc += bl[s];
    const long node = base + n;
    if (s < 2) out[node * 2 + s] = acc;
    else out[(long)n_nodes * 2 + node * 21 + (s - 2)] = acc;
  }
}

static inline char* align_up(char* p, size_t a) {
  return (char*)(((uintptr_t)p + a - 1) & ~(uintptr_t)(a - 1));
}

extern "C" void kernel_launch(void* const* d_in, const int* in_sizes, int n_in,
                              void* d_out, int out_size, void* d_ws, size_t ws_size,
                              hipStream_t stream) {
  const float* v    = (const float*)d_in[0];
  const int*   esrc = (const int*)d_in[1];
  const int*   edst = (const int*)d_in[2];
  const int*   erel = (const int*)d_in[3];
  const float* norm = (const float*)d_in[4];
  const float* W1   = (const float*)d_in[5];
  const float* W2   = (const float*)d_in[6];
  const float* W3   = (const float*)d_in[7];
  const float* Wa   = (const float*)d_in[8];
  const float* ba   = (const float*)d_in[9];
  const float* Wb   = (const float*)d_in[10];
  const float* bb   = (const float*)d_in[11];

  const int nN = in_sizes[0] / D;       // 100000
  const int E  = in_sizes[1];           // 1200000
  const int nb = (nN + BSZ - 1) >> BSH; // 512-node buckets -> 196

  // ---- workspace layout
  char* p = (char*)d_ws;
  bf16_t* hr = (bf16_t*)p;            p += 3L * nN * D * sizeof(bf16_t);
  p = align_up(p, 16);
  bf16_t* xb = (bf16_t*)p;            p += (long)nN * D * sizeof(bf16_t);
  p = align_up(p, 16);
  float* bufA = (float*)p;            p += (long)nN * D * sizeof(float);
  float* bufB = (float*)p;            p += (long)nN * D * sizeof(float);
  int* deg      = (int*)p;            p += (long)nN * sizeof(int);
  int* offs     = (int*)p;            p += (long)nN * sizeof(int);
  int* bdeg     = (int*)p;            p += (long)nb * sizeof(int);
  int* boffs    = (int*)p;            p += (long)(nb + 1) * sizeof(int);
  int* bcur     = (int*)p;            p += (long)nb * sizeof(int);
  p = align_up(p, 16);
  int2* edgebuf = (int2*)p;           p += (long)E * sizeof(int2);
  int2* binpay  = (int2*)p;           p += (long)E * sizeof(int2);

  const int tblocks = (nN + 63) / 64;
  const int gblocks = (int)(((long)nN * 8 + 255) / 256);
  const int hblocks = (E + ABLK - 1) / ABLK;
  const int cblocks = (nN * D / 4 + 255) / 256;

  // ---- CSR build (bucket-level histogram only; once per call)
  zero_kernel<<<1, 512, 0, stream>>>(bdeg, bcur, nb);
  bhist_kernel<<<hblocks, ATHR, 0, stream>>>(edst, bdeg, E, nb);
  bscan_kernel<<<1, 512, 0, stream>>>(bdeg, boffs, nb);
  binA_kernel<<<hblocks, ATHR, 0, stream>>>(esrc, edst, erel, norm, boffs, bcur,
                                            binpay, E, nb);
  binB_kernel<<<nb, 512, 0, stream>>>(binpay, boffs, edgebuf, deg, offs, nN);

  // ---- layer 1: v -> bufA (no skip); xb = bf16(v)
  conv_kernel<<<cblocks, 256, 0, stream>>>(v, xb, nN * D / 4);
  transform_kernel<<<tblocks, 256, 0, stream>>>(xb, W1, hr, nN);
  gather_kernel<<<gblocks, 256, 0, stream>>>(hr, edgebuf, offs, deg, nullptr,
                                             bufA, xb, nN);

  // ---- layer 2: bufA -> bufB (skip); xb = bf16(bufB)
  transform_kernel<<<tblocks, 256, 0, stream>>>(xb, W2, hr, nN);
  gather_kernel<<<gblocks, 256, 0, stream>>>(hr, edgebuf, offs, deg, bufA,
                                             bufB, xb, nN);

  // ---- layer 3: bufB -> bufA (skip); final (no xb needed)
  transform_kernel<<<tblocks, 256, 0, stream>>>(xb, W3, hr, nN);
  gather_kernel<<<gblocks, 256, 0, stream>>>(hr, edgebuf, offs, deg, bufB,
                                             bufA, nullptr, nN);

  // ---- heads
  heads_kernel<<<tblocks, 256, 0, stream>>>(bufA, Wa, ba, Wb, bb, (float*)d_out, nN);
}

// Round 17
// 236.655 us; speedup vs baseline: 1.1972x; 1.1090x over previous
//
#include <hip/hip_runtime.h>

#define D 64
#define NREL 3
#define SRC_MASK 0x1FFFF      // 17 bits: N=100000 < 2^17
#define ATHR 512
#define APT 8
#define ABLK (ATHR * APT)     // 4096 edges per block (bhist, binA)
#define BSH 9                 // 512-node buckets
#define BSZ 512

typedef unsigned short bf16_t;
typedef __attribute__((ext_vector_type(8))) short short8v;   // 8 bf16 = 4 VGPRs
typedef __attribute__((ext_vector_type(4))) float float4v;

__device__ __forceinline__ float bf2f(unsigned int u16) {
  return __uint_as_float(u16 << 16);
}
__device__ __forceinline__ unsigned int f2bf(float f) {
  unsigned int x = __float_as_uint(f);
  return (x + 0x7fffu + ((x >> 16) & 1u)) >> 16;  // round-to-nearest-even
}

// ---------------- tiny zero (R12-verified: replaces 2x ~40us fill dispatches) ----
__global__ __launch_bounds__(512) void zero_kernel(int* __restrict__ a,
                                                   int* __restrict__ b, int n) {
  const int t = threadIdx.x;
  for (int i = t; i < n; i += 512) { a[i] = 0; b[i] = 0; }
}

// ---------------- transform via MFMA (R11-verified: 4x faster than VALU) ----------
// F32IN: read f32 input and convert in-register (folds the old conv_kernel).
template <bool F32IN>
__global__ __launch_bounds__(256) void transform_kernel(
    const void* __restrict__ xin, const float* __restrict__ W,
    bf16_t* __restrict__ hr, int n_nodes) {
  __shared__ bf16_t wt[NREL * 64 * 72];  // 27.6 KB
  const int tid = threadIdx.x;

  for (int idx = tid; idx < NREL * 64 * 64; idx += 256) {
    const int r = idx >> 12;
    const int k = (idx >> 6) & 63;
    const int od = idx & 63;
    wt[(r * 64 + od) * 72 + k] = (bf16_t)f2bf(W[idx]);
  }
  __syncthreads();

  const int wid = tid >> 6;
  const int lane = tid & 63;
  const int n0 = blockIdx.x * 64 + wid * 16;
  if (n0 >= n_nodes) return;

  short8v bx0, bx1;
  if constexpr (F32IN) {
    const float* xrow =
        (const float*)xin + (long)(n0 + (lane & 15)) * 64 + (lane >> 4) * 8;
    const float4 f0 = *reinterpret_cast<const float4*>(xrow);
    const float4 f1 = *reinterpret_cast<const float4*>(xrow + 4);
    const float4 f2 = *reinterpret_cast<const float4*>(xrow + 32);
    const float4 f3 = *reinterpret_cast<const float4*>(xrow + 36);
    bx0[0] = (short)f2bf(f0.x); bx0[1] = (short)f2bf(f0.y);
    bx0[2] = (short)f2bf(f0.z); bx0[3] = (short)f2bf(f0.w);
    bx0[4] = (short)f2bf(f1.x); bx0[5] = (short)f2bf(f1.y);
    bx0[6] = (short)f2bf(f1.z); bx0[7] = (short)f2bf(f1.w);
    bx1[0] = (short)f2bf(f2.x); bx1[1] = (short)f2bf(f2.y);
    bx1[2] = (short)f2bf(f2.z); bx1[3] = (short)f2bf(f2.w);
    bx1[4] = (short)f2bf(f3.x); bx1[5] = (short)f2bf(f3.y);
    bx1[6] = (short)f2bf(f3.z); bx1[7] = (short)f2bf(f3.w);
  } else {
    const bf16_t* xrow =
        (const bf16_t*)xin + (long)(n0 + (lane & 15)) * 64 + (lane >> 4) * 8;
    bx0 = *reinterpret_cast<const short8v*>(xrow);
    bx1 = *reinterpret_cast<const short8v*>(xrow + 32);
  }

  const int node = n0 + (lane & 15);
#pragma unroll
  for (int r = 0; r < NREL; ++r) {
#pragma unroll
    for (int t = 0; t < 4; ++t) {
      const bf16_t* wrow =
          &wt[(r * 64 + t * 16 + (lane & 15)) * 72 + (lane >> 4) * 8];
      const short8v a0 = *reinterpret_cast<const short8v*>(wrow);
      const short8v a1 = *reinterpret_cast<const short8v*>(wrow + 32);
      float4v acc = {0.f, 0.f, 0.f, 0.f};
      acc = __builtin_amdgcn_mfma_f32_16x16x32_bf16(a0, bx0, acc, 0, 0, 0);
      acc = __builtin_amdgcn_mfma_f32_16x16x32_bf16(a1, bx1, acc, 0, 0, 0);
      const int od = t * 16 + (lane >> 4) * 4;
      uint2 o;
      o.x = f2bf(acc[0]) | (f2bf(acc[1]) << 16);
      o.y = f2bf(acc[2]) | (f2bf(acc[3]) << 16);
      *reinterpret_cast<uint2*>(&hr[((long)r * n_nodes + node) * 64 + od]) = o;
    }
  }
}

// ---------------- CSR build (bucket-level only; no node-level atomics) ----------
__global__ __launch_bounds__(ATHR) void bhist_kernel(
    const int* __restrict__ dst, int* __restrict__ bdeg, int n_edges, int nb) {
  __shared__ int cnt[200];
  const int t = threadIdx.x;
  for (int b = t; b < nb; b += ATHR) cnt[b] = 0;
  __syncthreads();
  const long e0 = (long)blockIdx.x * ABLK;
#pragma unroll
  for (int i = 0; i < APT; ++i) {
    const long e = e0 + t + (long)i * ATHR;
    if (e < n_edges) atomicAdd(&cnt[dst[e] >> BSH], 1);
  }
  __syncthreads();
  for (int b = t; b < nb; b += ATHR)
    if (cnt[b]) atomicAdd(&bdeg[b], cnt[b]);
}

// Single block: exclusive scan of bdeg[nb] -> boffs[nb+1] (nb <= 512).
__global__ __launch_bounds__(512) void bscan_kernel(
    const int* __restrict__ bdeg, int* __restrict__ boffs, int nb) {
  __shared__ int s[512];
  const int t = threadIdx.x;
  const int v = (t < nb) ? bdeg[t] : 0;
  s[t] = v;
  __syncthreads();
  for (int off = 1; off < 512; off <<= 1) {
    const int add = (t >= off) ? s[t - off] : 0;
    __syncthreads();
    s[t] += add;
    __syncthreads();
  }
  if (t < nb) boffs[t] = s[t] - v;
  if (t == 511) boffs[nb] = s[nb - 1];
}

// Phase A (one-pass, 4096 edges/block; packed payload src|rel|dlo — R16-verified).
__global__ __launch_bounds__(ATHR) void binA_kernel(
    const int* __restrict__ src, const int* __restrict__ dst,
    const int* __restrict__ rel, const float* __restrict__ norm,
    const int* __restrict__ boffs, int* __restrict__ bcur,
    int2* __restrict__ binpay, int n_edges, int nb) {
  __shared__ int cnt[200];
  __shared__ int basea[200];
  const int t = threadIdx.x;
  const long e0 = (long)blockIdx.x * ABLK;

  for (int b = t; b < nb; b += ATHR) cnt[b] = 0;
  __syncthreads();

  int2 pay[APT];
  int bk[APT], slot[APT];
#pragma unroll
  for (int i = 0; i < APT; ++i) {
    const long e = e0 + t + (long)i * ATHR;
    if (e < n_edges) {
      const int d = dst[e];
      bk[i] = d >> BSH;
      pay[i] = make_int2(src[e] | (rel[e] << 17) | ((d & (BSZ - 1)) << 19),
                         __float_as_int(norm[e]));
      slot[i] = atomicAdd(&cnt[bk[i]], 1);
    } else {
      bk[i] = -1;
    }
  }
  __syncthreads();

  for (int b = t; b < nb; b += ATHR) {
    const int c = cnt[b];
    basea[b] = c ? (boffs[b] + atomicAdd(&bcur[b], c)) : 0;
  }
  __syncthreads();

#pragma unroll
  for (int i = 0; i < APT; ++i) {
    if (bk[i] >= 0) binpay[basea[bk[i]] + slot[i]] = pay[i];
  }
}

// Phase B: one 512-thread block per 512-node bucket (R16-verified).
__global__ __launch_bounds__(512) void binB_kernel(
    const int2* __restrict__ binpay, const int* __restrict__ boffs,
    int2* __restrict__ edgebuf, int* __restrict__ deg, int* __restrict__ offs,
    int n_nodes) {
  __shared__ int cnt[512];
  __shared__ int ss[512];
  __shared__ int cur[512];
  const int b = blockIdx.x;
  const int t = threadIdx.x;
  cnt[t] = 0;
  __syncthreads();
  const int start = boffs[b];
  const int end = boffs[b + 1];
  for (int i = start + t; i < end; i += 512)
    atomicAdd(&cnt[((unsigned)binpay[i].x >> 19) & (BSZ - 1)], 1);
  __syncthreads();
  const int v = cnt[t];
  ss[t] = v;
  __syncthreads();
  for (int off = 1; off < 512; off <<= 1) {
    const int add = (t >= off) ? ss[t - off] : 0;
    __syncthreads();
    ss[t] += add;
    __syncthreads();
  }
  const int excl = ss[t] - v;
  cur[t] = excl;
  const int node = (b << BSH) + t;
  if (node < n_nodes) {
    deg[node] = v;
    offs[node] = start + excl;
  }
  __syncthreads();
  for (int i = start + t; i < end; i += 512) {
    const int2 pay = binpay[i];
    const int dl = ((unsigned)pay.x >> 19) & (BSZ - 1);
    const int pos = start + atomicAdd(&cur[dl], 1);
    edgebuf[pos] = pay;
  }
}

// ---------------- gather core (8 threads/node, uint4 hr reads) ----------------
__device__ __forceinline__ void gather_core(
    const bf16_t* __restrict__ hr, const int2* __restrict__ edgebuf,
    int beg, int cnt, int n_nodes, int c, float* a /*[8]*/) {
  float acc0[8], acc1[8];
#pragma unroll
  for (int j = 0; j < 8; ++j) { acc0[j] = 0.f; acc1[j] = 0.f; }

  int i = 0;
  for (; i + 3 < cnt; i += 4) {
    const int2 e0 = edgebuf[beg + i];
    const int2 e1 = edgebuf[beg + i + 1];
    const int2 e2 = edgebuf[beg + i + 2];
    const int2 e3 = edgebuf[beg + i + 3];
    const uint4 v0 = *reinterpret_cast<const uint4*>(
        &hr[((long)((((unsigned)e0.x) >> 17) & 3) * n_nodes + (e0.x & SRC_MASK)) * 64 + c]);
    const uint4 v1 = *reinterpret_cast<const uint4*>(
        &hr[((long)((((unsigned)e1.x) >> 17) & 3) * n_nodes + (e1.x & SRC_MASK)) * 64 + c]);
    const uint4 v2 = *reinterpret_cast<const uint4*>(
        &hr[((long)((((unsigned)e2.x) >> 17) & 3) * n_nodes + (e2.x & SRC_MASK)) * 64 + c]);
    const uint4 v3 = *reinterpret_cast<const uint4*>(
        &hr[((long)((((unsigned)e3.x) >> 17) & 3) * n_nodes + (e3.x & SRC_MASK)) * 64 + c]);
    const float n0 = __int_as_float(e0.y), n1 = __int_as_float(e1.y);
    const float n2 = __int_as_float(e2.y), n3 = __int_as_float(e3.y);
    const unsigned int w0[4] = {v0.x, v0.y, v0.z, v0.w};
    const unsigned int w1[4] = {v1.x, v1.y, v1.z, v1.w};
    const unsigned int w2[4] = {v2.x, v2.y, v2.z, v2.w};
    const unsigned int w3[4] = {v3.x, v3.y, v3.z, v3.w};
#pragma unroll
    for (int j = 0; j < 4; ++j) {
      acc0[2 * j + 0] += bf2f(w0[j] & 0xffff) * n0;
      acc0[2 * j + 1] += bf2f(w0[j] >> 16) * n0;
      acc1[2 * j + 0] += bf2f(w1[j] & 0xffff) * n1;
      acc1[2 * j + 1] += bf2f(w1[j] >> 16) * n1;
      acc0[2 * j + 0] += bf2f(w2[j] & 0xffff) * n2;
      acc0[2 * j + 1] += bf2f(w2[j] >> 16) * n2;
      acc1[2 * j + 0] += bf2f(w3[j] & 0xffff) * n3;
      acc1[2 * j + 1] += bf2f(w3[j] >> 16) * n3;
    }
  }
  for (; i < cnt; ++i) {
    const int2 ea = edgebuf[beg + i];
    const float na = __int_as_float(ea.y);
    const uint4 va = *reinterpret_cast<const uint4*>(
        &hr[((long)((((unsigned)ea.x) >> 17) & 3) * n_nodes + (ea.x & SRC_MASK)) * 64 + c]);
    const unsigned int wa[4] = {va.x, va.y, va.z, va.w};
#pragma unroll
    for (int j = 0; j < 4; ++j) {
      acc0[2 * j + 0] += bf2f(wa[j] & 0xffff) * na;
      acc0[2 * j + 1] += bf2f(wa[j] >> 16) * na;
    }
  }
#pragma unroll
  for (int j = 0; j < 8; ++j) a[j] = acc0[j] + acc1[j];
}

// ---------------- fused gather + skip + relu (layers 1-2) ----------------
__global__ __launch_bounds__(256) void gather_kernel(
    const bf16_t* __restrict__ hr, const int2* __restrict__ edgebuf,
    const int* __restrict__ offs, const int* __restrict__ deg,
    const float* __restrict__ skip, float* __restrict__ out,
    bf16_t* __restrict__ xbout, int n_nodes) {
  const long gid = (long)blockIdx.x * 256 + threadIdx.x;
  const int n = (int)(gid >> 3);
  if (n >= n_nodes) return;
  const int c = (int)(gid & 7) * 8;

  float a[8];
  gather_core(hr, edgebuf, offs[n], deg[n], n_nodes, c, a);
  if (skip != nullptr) {
    const float4 s0 = *reinterpret_cast<const float4*>(&skip[(long)n * 64 + c]);
    const float4 s1 = *reinterpret_cast<const float4*>(&skip[(long)n * 64 + c + 4]);
    a[0] += s0.x; a[1] += s0.y; a[2] += s0.z; a[3] += s0.w;
    a[4] += s1.x; a[5] += s1.y; a[6] += s1.z; a[7] += s1.w;
  }
#pragma unroll
  for (int j = 0; j < 8; ++j) a[j] = fmaxf(a[j], 0.f);
  float4 o0 = {a[0], a[1], a[2], a[3]};
  float4 o1 = {a[4], a[5], a[6], a[7]};
  *reinterpret_cast<float4*>(&out[(long)n * 64 + c]) = o0;
  *reinterpret_cast<float4*>(&out[(long)n * 64 + c + 4]) = o1;
  uint4 ob;
  ob.x = f2bf(a[0]) | (f2bf(a[1]) << 16);
  ob.y = f2bf(a[2]) | (f2bf(a[3]) << 16);
  ob.z = f2bf(a[4]) | (f2bf(a[5]) << 16);
  ob.w = f2bf(a[6]) | (f2bf(a[7]) << 16);
  *reinterpret_cast<uint4*>(&xbout[(long)n * 64 + c]) = ob;
}

// ---------------- layer-3: gather + skip + relu + BOTH HEADS fused ----------------
// Block owns 32 nodes (3125 blocks exactly). x tile parked in LDS; heads use
// the R9-verified transposed wlt[k][s] layout (conflict-free). Eliminates the
// separate heads kernel AND the 51 MB bufA write+read round-trip.
__global__ __launch_bounds__(256) void gather_heads_kernel(
    const bf16_t* __restrict__ hr, const int2* __restrict__ edgebuf,
    const int* __restrict__ offs, const int* __restrict__ deg,
    const float* __restrict__ skip, const float* __restrict__ Wa,
    const float* __restrict__ ba, const float* __restrict__ Wb,
    const float* __restrict__ bb, float* __restrict__ out, int n_nodes) {
  __shared__ float xs[32][72];   // 9.2 KB, float4-aligned rows
  __shared__ float wlt[64][24];  // [k][s]
  __shared__ float bl[23];
  const int tid = threadIdx.x;

  for (int idx = tid; idx < 2 * 64; idx += 256) wlt[idx & 63][idx >> 6] = Wa[idx];
  for (int idx = tid; idx < 21 * 64; idx += 256)
    wlt[idx & 63][2 + (idx >> 6)] = Wb[idx];
  if (tid < 2) bl[tid] = ba[tid];
  else if (tid < 23) bl[tid] = bb[tid - 2];

  const int nbase = blockIdx.x * 32;
  const int nl = tid >> 3;
  const int n = nbase + nl;
  const int c = (tid & 7) * 8;

  if (n < n_nodes) {
    float a[8];
    gather_core(hr, edgebuf, offs[n], deg[n], n_nodes, c, a);
    if (skip != nullptr) {
      const float4 s0 = *reinterpret_cast<const float4*>(&skip[(long)n * 64 + c]);
      const float4 s1 = *reinterpret_cast<const float4*>(&skip[(long)n * 64 + c + 4]);
      a[0] += s0.x; a[1] += s0.y; a[2] += s0.z; a[3] += s0.w;
      a[4] += s1.x; a[5] += s1.y; a[6] += s1.z; a[7] += s1.w;
    }
#pragma unroll
    for (int j = 0; j < 8; ++j) a[j] = fmaxf(a[j], 0.f);
    float4 o0 = {a[0], a[1], a[2], a[3]};
    float4 o1 = {a[4], a[5], a[6], a[7]};
    *reinterpret_cast<float4*>(&xs[nl][c]) = o0;
    *reinterpret_cast<float4*>(&xs[nl][c + 4]) = o1;
  }
  __syncthreads();

  const int nrows = min(32, n_nodes - nbase);
  for (int idx = tid; idx < nrows * 23; idx += 256) {
    const int nn = idx / 23;
    const int s = idx % 23;
    float acc = 0.f;
#pragma unroll
    for (int k = 0; k < 64; ++k) acc += xs[nn][k] * wlt[k][s];
    acc += bl[s];
    const long node = nbase + nn;
    if (s < 2) out[node * 2 + s] = acc;
    else out[(long)n_nodes * 2 + node * 21 + (s - 2)] = acc;
  }
}

static inline char* align_up(char* p, size_t a) {
  return (char*)(((uintptr_t)p + a - 1) & ~(uintptr_t)(a - 1));
}

extern "C" void kernel_launch(void* const* d_in, const int* in_sizes, int n_in,
                              void* d_out, int out_size, void* d_ws, size_t ws_size,
                              hipStream_t stream) {
  const float* v    = (const float*)d_in[0];
  const int*   esrc = (const int*)d_in[1];
  const int*   edst = (const int*)d_in[2];
  const int*   erel = (const int*)d_in[3];
  const float* norm = (const float*)d_in[4];
  const float* W1   = (const float*)d_in[5];
  const float* W2   = (const float*)d_in[6];
  const float* W3   = (const float*)d_in[7];
  const float* Wa   = (const float*)d_in[8];
  const float* ba   = (const float*)d_in[9];
  const float* Wb   = (const float*)d_in[10];
  const float* bb   = (const float*)d_in[11];

  const int nN = in_sizes[0] / D;       // 100000
  const int E  = in_sizes[1];           // 1200000
  const int nb = (nN + BSZ - 1) >> BSH; // 512-node buckets -> 196

  // ---- workspace layout
  char* p = (char*)d_ws;
  bf16_t* hr = (bf16_t*)p;            p += 3L * nN * D * sizeof(bf16_t);
  p = align_up(p, 16);
  bf16_t* xb = (bf16_t*)p;            p += (long)nN * D * sizeof(bf16_t);
  p = align_up(p, 16);
  float* bufA = (float*)p;            p += (long)nN * D * sizeof(float);
  float* bufB = (float*)p;            p += (long)nN * D * sizeof(float);
  int* deg      = (int*)p;            p += (long)nN * sizeof(int);
  int* offs     = (int*)p;            p += (long)nN * sizeof(int);
  int* bdeg     = (int*)p;            p += (long)nb * sizeof(int);
  int* boffs    = (int*)p;            p += (long)(nb + 1) * sizeof(int);
  int* bcur     = (int*)p;            p += (long)nb * sizeof(int);
  p = align_up(p, 16);
  int2* edgebuf = (int2*)p;           p += (long)E * sizeof(int2);
  int2* binpay  = (int2*)p;           p += (long)E * sizeof(int2);

  const int tblocks = (nN + 63) / 64;
  const int gblocks = (int)(((long)nN * 8 + 255) / 256);
  const int ghblocks = (nN + 31) / 32;
  const int hblocks = (E + ABLK - 1) / ABLK;

  // ---- CSR build (bucket-level histogram only; once per call)
  zero_kernel<<<1, 512, 0, stream>>>(bdeg, bcur, nb);
  bhist_kernel<<<hblocks, ATHR, 0, stream>>>(edst, bdeg, E, nb);
  bscan_kernel<<<1, 512, 0, stream>>>(bdeg, boffs, nb);
  binA_kernel<<<hblocks, ATHR, 0, stream>>>(esrc, edst, erel, norm, boffs, bcur,
                                            binpay, E, nb);
  binB_kernel<<<nb, 512, 0, stream>>>(binpay, boffs, edgebuf, deg, offs, nN);

  // ---- layer 1: v (f32, converted in-kernel) -> hr; gather -> bufA + xb
  transform_kernel<true><<<tblocks, 256, 0, stream>>>(v, W1, hr, nN);
  gather_kernel<<<gblocks, 256, 0, stream>>>(hr, edgebuf, offs, deg, nullptr,
                                             bufA, xb, nN);

  // ---- layer 2: xb -> hr; gather(skip=bufA) -> bufB + xb
  transform_kernel<false><<<tblocks, 256, 0, stream>>>(xb, W2, hr, nN);
  gather_kernel<<<gblocks, 256, 0, stream>>>(hr, edgebuf, offs, deg, bufA,
                                             bufB, xb, nN);

  // ---- layer 3: xb -> hr; gather(skip=bufB) + heads -> d_out (fused)
  transform_kernel<false><<<tblocks, 256, 0, stream>>>(xb, W3, hr, nN);
  gather_heads_kernel<<<ghblocks, 256, 0, stream>>>(hr, edgebuf, offs, deg, bufB,
                                                    Wa, ba, Wb, bb,
                                                    (float*)d_out, nN);
}